// Round 1
// baseline (369.478 us; speedup 1.0000x reference)
//
#include <hip/hip_runtime.h>

constexpr int DIM  = 6;
constexpr int RPT  = 4;          // rows per thread
constexpr float NEG = 0.01f;

// One layer applied to all RPT rows held in registers.
// Weights/biases are uniform -> scalar loads, amortized over RPT rows.
template<bool RELU>
__device__ __forceinline__ void layer_all(const float* __restrict__ Wp,
                                          const float* __restrict__ bp,
                                          float (&x)[RPT][DIM]) {
    float Wr[DIM][DIM], br[DIM];
    #pragma unroll
    for (int j = 0; j < DIM; ++j) {
        br[j] = bp[j];
        #pragma unroll
        for (int k = 0; k < DIM; ++k) Wr[j][k] = Wp[j * DIM + k];
    }
    #pragma unroll
    for (int r = 0; r < RPT; ++r) {
        float y[DIM];
        #pragma unroll
        for (int j = 0; j < DIM; ++j) {
            float acc = br[j];
            #pragma unroll
            for (int k = 0; k < DIM; ++k)
                acc = fmaf(Wr[j][k], x[r][k], acc);
            y[j] = RELU ? fmaxf(acc, NEG * acc) : acc;
        }
        #pragma unroll
        for (int j = 0; j < DIM; ++j) x[r][j] = y[j];
    }
}

__global__ __launch_bounds__(256) void mlp19_kernel(
    const float* __restrict__ X,
    const float* __restrict__ Ws,
    const float* __restrict__ bs,
    const float* __restrict__ bounds,
    float* __restrict__ out, int B)
{
    const int g = blockIdx.x * blockDim.x + threadIdx.x;
    const int T = gridDim.x * blockDim.x;

    // normalization constants: w = x * sc + sh
    float sc[DIM], sh[DIM];
    #pragma unroll
    for (int k = 0; k < DIM; ++k) {
        const float lo = bounds[2 * k], hi = bounds[2 * k + 1];
        const float inv = 1.0f / (hi - lo);
        sc[k] = inv;
        sh[k] = -lo * inv;
    }

    float w[RPT][DIM];

    // ---- load + normalize ----
    #pragma unroll
    for (int r = 0; r < RPT; ++r) {
        const int row = g + r * T;
        if (row < B) {
            const float* xp = X + (size_t)row * DIM;
            const float2 p0 = *reinterpret_cast<const float2*>(xp + 0);
            const float2 p1 = *reinterpret_cast<const float2*>(xp + 2);
            const float2 p2 = *reinterpret_cast<const float2*>(xp + 4);
            w[r][0] = p0.x; w[r][1] = p0.y;
            w[r][2] = p1.x; w[r][3] = p1.y;
            w[r][4] = p2.x; w[r][5] = p2.y;
        } else {
            #pragma unroll
            for (int k = 0; k < DIM; ++k) w[r][k] = 0.0f;
        }
        #pragma unroll
        for (int k = 0; k < DIM; ++k)
            w[r][k] = fmaf(w[r][k], sc[k], sh[k]);
    }

    // ---- 4 residual blocks ----
    #pragma unroll
    for (int blk = 0; blk < 4; ++blk) {
        float res[RPT][DIM];
        #pragma unroll
        for (int r = 0; r < RPT; ++r)
            #pragma unroll
            for (int k = 0; k < DIM; ++k) res[r][k] = w[r][k];

        const int i0 = blk * 4;
        layer_all<true >(Ws + (i0 + 0) * 36, bs + (i0 + 0) * 6, w);
        layer_all<true >(Ws + (i0 + 1) * 36, bs + (i0 + 1) * 6, w);
        layer_all<true >(Ws + (i0 + 2) * 36, bs + (i0 + 2) * 6, w);
        layer_all<false>(Ws + (i0 + 3) * 36, bs + (i0 + 3) * 6, w);

        #pragma unroll
        for (int r = 0; r < RPT; ++r)
            #pragma unroll
            for (int k = 0; k < DIM; ++k) w[r][k] += res[r][k];
    }

    // ---- head ----
    layer_all<true >(Ws + 16 * 36, bs + 16 * 6, w);
    layer_all<true >(Ws + 17 * 36, bs + 17 * 6, w);
    layer_all<false>(Ws + 18 * 36, bs + 18 * 6, w);

    // ---- store ----
    #pragma unroll
    for (int r = 0; r < RPT; ++r) {
        const int row = g + r * T;
        if (row < B) {
            float* op = out + (size_t)row * DIM;
            *reinterpret_cast<float2*>(op + 0) = make_float2(w[r][0], w[r][1]);
            *reinterpret_cast<float2*>(op + 2) = make_float2(w[r][2], w[r][3]);
            *reinterpret_cast<float2*>(op + 4) = make_float2(w[r][4], w[r][5]);
        }
    }
}

extern "C" void kernel_launch(void* const* d_in, const int* in_sizes, int n_in,
                              void* d_out, int out_size, void* d_ws, size_t ws_size,
                              hipStream_t stream) {
    const float* X      = (const float*)d_in[0];
    const float* Ws     = (const float*)d_in[1];
    const float* bs     = (const float*)d_in[2];
    const float* bounds = (const float*)d_in[3];
    float* out = (float*)d_out;

    const int B = in_sizes[0] / DIM;
    const int block = 256;
    const int grid = (B + block * RPT - 1) / (block * RPT);
    hipLaunchKernelGGL(mlp19_kernel, dim3(grid), dim3(block), 0, stream,
                       X, Ws, bs, bounds, out, B);
}

// Round 2
// 225.569 us; speedup vs baseline: 1.6380x; 1.6380x over previous
//
#include <hip/hip_runtime.h>

constexpr int DIM = 6;
constexpr float NEG = 0.01f;

// One 6x6 layer, fully in registers. Weights/bias are wave-uniform ->
// compiler emits s_load; v_fma_f32 reads the weight straight from SGPR.
template<bool RELU>
__device__ __forceinline__ void layer(const float* __restrict__ W,
                                      const float* __restrict__ b,
                                      float (&x)[DIM]) {
    float y[DIM];
    #pragma unroll
    for (int j = 0; j < DIM; ++j) {
        float acc = b[j];
        #pragma unroll
        for (int k = 0; k < DIM; ++k)
            acc = fmaf(W[j * DIM + k], x[k], acc);
        y[j] = RELU ? fmaxf(acc, NEG * acc) : acc;
    }
    #pragma unroll
    for (int j = 0; j < DIM; ++j) x[j] = y[j];
}

__global__ __launch_bounds__(256, 4) void mlp19_kernel(
    const float* __restrict__ X,
    const float* __restrict__ Ws,
    const float* __restrict__ bs,
    const float* __restrict__ bounds,
    float* __restrict__ out, int B)
{
    const int row = blockIdx.x * blockDim.x + threadIdx.x;
    if (row >= B) return;

    // ---- load ----
    const float* xp = X + (size_t)row * DIM;
    const float2 p0 = *reinterpret_cast<const float2*>(xp + 0);
    const float2 p1 = *reinterpret_cast<const float2*>(xp + 2);
    const float2 p2 = *reinterpret_cast<const float2*>(xp + 4);

    float w[DIM] = {p0.x, p0.y, p1.x, p1.y, p2.x, p2.y};

    // ---- normalize: w = (x - lo) / (hi - lo) ----
    #pragma unroll
    for (int k = 0; k < DIM; ++k) {
        const float lo = bounds[2 * k], hi = bounds[2 * k + 1];
        const float inv = 1.0f / (hi - lo);
        w[k] = fmaf(w[k], inv, -lo * inv);
    }

    // ---- 4 residual blocks (NOT unrolled: one layer's weights live at a time) ----
    #pragma unroll 1
    for (int blk = 0; blk < 4; ++blk) {
        const float* Wb = Ws + (size_t)blk * 4 * 36;
        const float* bb = bs + (size_t)blk * 4 * 6;

        float res[DIM];
        #pragma unroll
        for (int k = 0; k < DIM; ++k) res[k] = w[k];

        layer<true >(Wb +   0, bb +  0, w);
        layer<true >(Wb +  36, bb +  6, w);
        layer<true >(Wb +  72, bb + 12, w);
        layer<false>(Wb + 108, bb + 18, w);

        #pragma unroll
        for (int k = 0; k < DIM; ++k) w[k] += res[k];
    }

    // ---- head ----
    layer<true >(Ws + 16 * 36, bs + 16 * 6, w);
    layer<true >(Ws + 17 * 36, bs + 17 * 6, w);
    layer<false>(Ws + 18 * 36, bs + 18 * 6, w);

    // ---- store ----
    float* op = out + (size_t)row * DIM;
    *reinterpret_cast<float2*>(op + 0) = make_float2(w[0], w[1]);
    *reinterpret_cast<float2*>(op + 2) = make_float2(w[2], w[3]);
    *reinterpret_cast<float2*>(op + 4) = make_float2(w[4], w[5]);
}

extern "C" void kernel_launch(void* const* d_in, const int* in_sizes, int n_in,
                              void* d_out, int out_size, void* d_ws, size_t ws_size,
                              hipStream_t stream) {
    const float* X      = (const float*)d_in[0];
    const float* Ws     = (const float*)d_in[1];
    const float* bs     = (const float*)d_in[2];
    const float* bounds = (const float*)d_in[3];
    float* out = (float*)d_out;

    const int B = in_sizes[0] / DIM;
    const int block = 256;
    const int grid = (B + block - 1) / block;
    hipLaunchKernelGGL(mlp19_kernel, dim3(grid), dim3(block), 0, stream,
                       X, Ws, bs, bounds, out, B);
}

// Round 3
// 208.963 us; speedup vs baseline: 1.7682x; 1.0795x over previous
//
#include <hip/hip_runtime.h>

typedef float v2f __attribute__((ext_vector_type(2)));

constexpr int DIM = 6;
constexpr float NEG = 0.01f;

// One 6x6 layer applied to 2 rows held as packed float2 (v_pk_* ops).
// Weights/bias are wave-uniform -> scalar loads; splat feeds both halves.
template<bool RELU>
__device__ __forceinline__ void layer2(const float* __restrict__ W,
                                       const float* __restrict__ b,
                                       v2f (&x)[DIM]) {
    v2f y[DIM];
    #pragma unroll
    for (int j = 0; j < DIM; ++j) {
        v2f acc = {b[j], b[j]};
        #pragma unroll
        for (int k = 0; k < DIM; ++k) {
            const float wjk = W[j * DIM + k];
            const v2f wv = {wjk, wjk};
            acc = __builtin_elementwise_fma(wv, x[k], acc);
        }
        if (RELU) {
            const v2f nacc = acc * (v2f){NEG, NEG};
            y[j] = __builtin_elementwise_max(acc, nacc);
        } else {
            y[j] = acc;
        }
    }
    #pragma unroll
    for (int j = 0; j < DIM; ++j) x[j] = y[j];
}

__device__ __forceinline__ void run_net(const float* __restrict__ Ws,
                                        const float* __restrict__ bs,
                                        v2f (&w)[DIM]) {
    #pragma unroll 1
    for (int blk = 0; blk < 4; ++blk) {
        const float* Wb = Ws + (size_t)blk * 4 * 36;
        const float* bb = bs + (size_t)blk * 4 * 6;

        v2f res[DIM];
        #pragma unroll
        for (int k = 0; k < DIM; ++k) res[k] = w[k];

        layer2<true >(Wb +   0, bb +  0, w);
        layer2<true >(Wb +  36, bb +  6, w);
        layer2<true >(Wb +  72, bb + 12, w);
        layer2<false>(Wb + 108, bb + 18, w);

        #pragma unroll
        for (int k = 0; k < DIM; ++k) w[k] += res[k];
    }
    layer2<true >(Ws + 16 * 36, bs + 16 * 6, w);
    layer2<true >(Ws + 17 * 36, bs + 17 * 6, w);
    layer2<false>(Ws + 18 * 36, bs + 18 * 6, w);
}

__global__ __launch_bounds__(256, 4) void mlp19_kernel(
    const float* __restrict__ X,
    const float* __restrict__ Ws,
    const float* __restrict__ bs,
    const float* __restrict__ bounds,
    float* __restrict__ out, int B)
{
    const int g  = blockIdx.x * blockDim.x + threadIdx.x;
    const int r0 = 2 * g;
    if (r0 >= B) return;
    const bool full = (r0 + 1) < B;

    // normalization constants: w = x*sc + sh (uniform -> SGPR)
    float sc[DIM], sh[DIM];
    #pragma unroll
    for (int k = 0; k < DIM; ++k) {
        const float lo = bounds[2 * k], hi = bounds[2 * k + 1];
        const float inv = 1.0f / (hi - lo);
        sc[k] = inv;
        sh[k] = -lo * inv;
    }

    v2f w[DIM];
    const float* xp = X + (size_t)r0 * DIM;

    if (full) {
        // 12 contiguous floats = rows r0,r0+1 ; 48B/lane, coalesced
        const float4 a = *reinterpret_cast<const float4*>(xp + 0); // r0[0..3]
        const float4 b = *reinterpret_cast<const float4*>(xp + 4); // r0[4..5], r1[0..1]
        const float4 c = *reinterpret_cast<const float4*>(xp + 8); // r1[2..5]
        w[0] = (v2f){a.x, b.z};
        w[1] = (v2f){a.y, b.w};
        w[2] = (v2f){a.z, c.x};
        w[3] = (v2f){a.w, c.y};
        w[4] = (v2f){b.x, c.z};
        w[5] = (v2f){b.y, c.w};
    } else {
        #pragma unroll
        for (int k = 0; k < DIM; ++k) w[k] = (v2f){xp[k], 0.0f};
    }

    #pragma unroll
    for (int k = 0; k < DIM; ++k) {
        const v2f scv = {sc[k], sc[k]};
        const v2f shv = {sh[k], sh[k]};
        w[k] = __builtin_elementwise_fma(w[k], scv, shv);
    }

    run_net(Ws, bs, w);

    float* op = out + (size_t)r0 * DIM;
    if (full) {
        const float4 o0 = {w[0].x, w[1].x, w[2].x, w[3].x};
        const float4 o1 = {w[4].x, w[5].x, w[0].y, w[1].y};
        const float4 o2 = {w[2].y, w[3].y, w[4].y, w[5].y};
        *reinterpret_cast<float4*>(op + 0) = o0;
        *reinterpret_cast<float4*>(op + 4) = o1;
        *reinterpret_cast<float4*>(op + 8) = o2;
    } else {
        #pragma unroll
        for (int k = 0; k < DIM; ++k) op[k] = w[k].x;
    }
}

extern "C" void kernel_launch(void* const* d_in, const int* in_sizes, int n_in,
                              void* d_out, int out_size, void* d_ws, size_t ws_size,
                              hipStream_t stream) {
    const float* X      = (const float*)d_in[0];
    const float* Ws     = (const float*)d_in[1];
    const float* bs     = (const float*)d_in[2];
    const float* bounds = (const float*)d_in[3];
    float* out = (float*)d_out;

    const int B = in_sizes[0] / DIM;
    const int block = 256;
    const int rows_per_block = block * 2;
    const int grid = (B + rows_per_block - 1) / rows_per_block;
    hipLaunchKernelGGL(mlp19_kernel, dim3(grid), dim3(block), 0, stream,
                       X, Ws, bs, bounds, out, B);
}